// Round 5
// baseline (849.217 us; speedup 1.0000x reference)
//
#include <hip/hip_runtime.h>
#include <math.h>

#define IN_CH 512
#define HID 128
#define NCLASS 40
#define SCAN_CHUNK 2048
#define FILL_CHUNKS 2048   // edge chunks for range-partitioned fill

typedef __attribute__((ext_vector_type(8))) short short8;
typedef __attribute__((ext_vector_type(4))) float float4v;

static __device__ inline ushort f2bf(float f) {
    unsigned int u = __float_as_uint(f);
    u += 0x7fffu + ((u >> 16) & 1u);
    return (ushort)(u >> 16);
}
static __device__ inline float bf2f(ushort u) {
    return __uint_as_float(((unsigned int)u) << 16);
}
// packed-bf16 halves -> float without shifts where possible
static __device__ inline float blo(unsigned int u) { return __uint_as_float(u << 16); }
static __device__ inline float bhi(unsigned int u) { return __uint_as_float(u & 0xffff0000u); }

// ---------------- degree count ----------------
__global__ void k_count(const int* __restrict__ dst, int E, int* __restrict__ cnt) {
    int i = blockIdx.x * blockDim.x + threadIdx.x;
    if (i < E) atomicAdd(&cnt[dst[i]], 1);
}

// ---------------- exclusive scan of cnt -> rowptr ----------------
__global__ __launch_bounds__(256) void k_scan_local(const int* __restrict__ cnt,
                                                    int* __restrict__ rowptr,
                                                    int* __restrict__ blocksum, int n) {
    __shared__ int ssum[256];
    int b = blockIdx.x, t = threadIdx.x;
    int base = b * SCAN_CHUNK + t * 8;
    int v[8], s = 0;
    #pragma unroll
    for (int i = 0; i < 8; ++i) {
        int idx = base + i;
        v[i] = (idx < n) ? cnt[idx] : 0;
        s += v[i];
    }
    ssum[t] = s;
    __syncthreads();
    for (int off = 1; off < 256; off <<= 1) {
        int x = (t >= off) ? ssum[t - off] : 0;
        __syncthreads();
        ssum[t] += x;
        __syncthreads();
    }
    int run = ssum[t] - s;
    #pragma unroll
    for (int i = 0; i < 8; ++i) {
        int idx = base + i;
        if (idx < n) rowptr[idx] = run;
        run += v[i];
    }
    if (t == 255) blocksum[b] = ssum[255];
}

__global__ void k_scan_blocksums(int* blocksum, int nb) {
    if (threadIdx.x == 0 && blockIdx.x == 0) {
        int acc = 0;
        for (int i = 0; i < nb; ++i) { int v = blocksum[i]; blocksum[i] = acc; acc += v; }
    }
}

// scan finalize + dinv computation fused (both N-parallel over cnt/rowptr)
__global__ void k_scan_add_dinv(int* __restrict__ rowptr, int* __restrict__ cursor,
                                const int* __restrict__ blocksum,
                                const int* __restrict__ cnt,
                                float* __restrict__ dinv, int n) {
    int i = blockIdx.x * blockDim.x + threadIdx.x;
    if (i < n) {
        int r = rowptr[i] + blocksum[i / SCAN_CHUNK];
        rowptr[i] = r;
        cursor[i] = r;
        dinv[i] = rsqrtf((float)cnt[i] + 1.0f);
    }
}

// ------- CSR fill, dst-range partitioned for L2 locality (round-3 form) -----
__global__ __launch_bounds__(256) void k_fill(const int* __restrict__ src,
                                              const int* __restrict__ dst,
                                              int* __restrict__ cursor,
                                              int* __restrict__ col, int E, int N) {
    int range = blockIdx.x & 7;
    int chunk = blockIdx.x >> 3;
    int r0 = (N >> 3) * range;
    int r1 = (range == 7) ? N : r0 + (N >> 3);
    int e0 = (int)((long long)E * chunk / FILL_CHUNKS);
    int e1 = (int)((long long)E * (chunk + 1) / FILL_CHUNKS);
    for (int e = e0 + threadIdx.x; e < e1; e += 256) {
        int d = dst[e];
        if (d >= r0 && d < r1) {
            int p = atomicAdd(&cursor[d], 1);
            col[p] = src[e];
        }
    }
}

// ---- W1 [512][128] -> W1t [128][512] bf16  +  W2 [128][40] -> W2t [48][128] ----
__global__ void k_wt(const float* __restrict__ W1, const float* __restrict__ W2,
                     ushort* __restrict__ W1t, ushort* __restrict__ W2t) {
    int i = blockIdx.x * blockDim.x + threadIdx.x;   // 65536 + 6144 = 71680
    if (i < HID * IN_CH) {
        int n = i >> 9;
        int k = i & 511;
        W1t[i] = f2bf(W1[k * HID + n]);
    } else {
        int q = i - HID * IN_CH;
        int n = q >> 7;
        int k = q & 127;
        float v = (n < NCLASS) ? W2[k * NCLASS + n] : 0.f;
        W2t[q] = f2bf(v);
    }
}

// ------- GEMM1 (MFMA bf16): [M,512] @ [512,128] -> dinv[m] * (.) -> bf16 -------
// Epilogue pre-scales each row by dinv[row]: downstream aggregation becomes a
// pure unweighted sum (no per-edge dinv load / multiply).
#define GBM 128
#define GBK 64
#define KP 72    // LDS row stride (bf16): 144 B -> worst 2-way bank aliasing (free)
__global__ __launch_bounds__(256) void k_gemm1_mfma(const float* __restrict__ X,
                                                    const ushort* __restrict__ W1t,
                                                    const float* __restrict__ dinv,
                                                    ushort* __restrict__ H, int M) {
    __shared__ ushort As[GBM * KP];   // 18.4 KB
    int t = threadIdx.x;
    int bm = blockIdx.x * GBM;
    int wave = t >> 6;
    int lane = t & 63;
    int m0w = (wave >> 1) * 64;
    int n0w = (wave & 1) * 64;
    int lrow = lane & 15;
    int quad = lane >> 4;

    float4v acc[4][4];
    #pragma unroll
    for (int i = 0; i < 4; ++i)
        #pragma unroll
        for (int j = 0; j < 4; ++j) acc[i][j] = (float4v)(0.f);

    int ar = t >> 1;
    int ah = (t & 1) * 32;
    int gmr = bm + ar;
    if (gmr >= M) gmr = M - 1;        // clamp: OOB C rows are never written
    const float* gA = &X[(size_t)gmr * IN_CH + ah];

    float4 pre[8];
    #pragma unroll
    for (int i = 0; i < 8; ++i) pre[i] = *(const float4*)(gA + i * 4);

    for (int k0 = 0; k0 < IN_CH; k0 += GBK) {
        #pragma unroll
        for (int i = 0; i < 4; ++i) {
            union { ushort u[8]; uint4 v; } pk;
            float4 f0 = pre[2 * i], f1 = pre[2 * i + 1];
            pk.u[0] = f2bf(f0.x); pk.u[1] = f2bf(f0.y);
            pk.u[2] = f2bf(f0.z); pk.u[3] = f2bf(f0.w);
            pk.u[4] = f2bf(f1.x); pk.u[5] = f2bf(f1.y);
            pk.u[6] = f2bf(f1.z); pk.u[7] = f2bf(f1.w);
            *(uint4*)&As[ar * KP + ah + i * 8] = pk.v;
        }
        if (k0 + GBK < IN_CH) {
            #pragma unroll
            for (int i = 0; i < 8; ++i)
                pre[i] = *(const float4*)(gA + k0 + GBK + i * 4);
        }
        __syncthreads();
        #pragma unroll
        for (int kk = 0; kk < GBK; kk += 32) {
            short8 af[4], bfr[4];
            #pragma unroll
            for (int j = 0; j < 4; ++j)
                bfr[j] = *(const short8*)&W1t[(size_t)(n0w + j * 16 + lrow) * IN_CH
                                              + k0 + kk + quad * 8];
            #pragma unroll
            for (int i = 0; i < 4; ++i)
                af[i] = *(const short8*)&As[(m0w + i * 16 + lrow) * KP + kk + quad * 8];
            #pragma unroll
            for (int i = 0; i < 4; ++i)
                #pragma unroll
                for (int j = 0; j < 4; ++j)
                    acc[i][j] = __builtin_amdgcn_mfma_f32_16x16x32_bf16(
                        af[i], bfr[j], acc[i][j], 0, 0, 0);
        }
        __syncthreads();
    }
    #pragma unroll
    for (int i = 0; i < 4; ++i) {
        #pragma unroll
        for (int r = 0; r < 4; ++r) {
            int gm = bm + m0w + i * 16 + quad * 4 + r;
            if (gm < M) {
                float di = dinv[gm];
                #pragma unroll
                for (int j = 0; j < 4; ++j)
                    H[(size_t)gm * HID + n0w + j * 16 + lrow] = f2bf(acc[i][j][r] * di);
            }
        }
    }
}

// ------- layer-1 aggregation, XCD channel-sliced -----------------------------
// slice = blockIdx % 8, matching MI355X round-robin block->XCD dispatch: each
// XCD gathers only its 16-channel (3.2 MB) slice of h1b -> L2-resident, so
// L2-miss traffic drops from ~195 MB (each XCD streams the whole 25.6 MB
// table) to ~26 MB total. Wave = one (node, slice); 16 lane-groups of 4 lanes
// gather 16 edges x 32 B per instruction; self-loop = virtual edge at jend.
// Rows pre-scaled by dinv[src]: the loop is a pure sum. Epilogue: *dm, +b1,
// relu, *dm (layer-2 pre-scale) -> packed bf16.
__global__ __launch_bounds__(1024) void k_agg1_slice(const int* __restrict__ rowptr,
                                                     const int* __restrict__ rowend,
                                                     const int* __restrict__ col,
                                                     const float* __restrict__ dinv,
                                                     const unsigned int* __restrict__ h1b,
                                                     const float* __restrict__ b1,
                                                     unsigned int* __restrict__ hb, int N) {
    int slice = blockIdx.x & 7;
    int wv = threadIdx.x >> 6;
    int lane = threadIdx.x & 63;
    int g  = lane >> 2;          // edge group 0..15
    int il = lane & 3;           // uint-pair within slice: channels slice*16+4*il..+3
    int m = (blockIdx.x >> 3) * 16 + wv;
    if (m >= N) m = N - 1;       // duplicate rows write identical bytes: benign
    int boff = slice * 8 + il * 2;
    float c0 = 0.f, c1 = 0.f, c2 = 0.f, c3 = 0.f;
    int j0 = rowptr[m], jend = rowend[m];
    int jv = jend + 1;           // +1 virtual self-loop edge at index jend
    for (int j = j0; j < jv; j += 16) {
        int jg = j + g;
        if (jg < jv) {
            int s = (jg < jend) ? col[jg] : m;
            uint2 v = *(const uint2*)&h1b[(size_t)s * 64 + boff];
            c0 += blo(v.x); c1 += bhi(v.x); c2 += blo(v.y); c3 += bhi(v.y);
        }
    }
    #pragma unroll
    for (int off = 4; off < 64; off <<= 1) {
        c0 += __shfl_xor(c0, off);
        c1 += __shfl_xor(c1, off);
        c2 += __shfl_xor(c2, off);
        c3 += __shfl_xor(c3, off);
    }
    if (g == 0) {
        float dm = dinv[m];
        float4 bb = *(const float4*)&b1[slice * 16 + il * 4];
        float h0 = fmaxf(fmaf(c0, dm, bb.x), 0.f) * dm;
        float h1 = fmaxf(fmaf(c1, dm, bb.y), 0.f) * dm;
        float h2 = fmaxf(fmaf(c2, dm, bb.z), 0.f) * dm;
        float h3 = fmaxf(fmaf(c3, dm, bb.w), 0.f) * dm;
        uint2 o;
        o.x = (unsigned int)f2bf(h0) | ((unsigned int)f2bf(h1) << 16);
        o.y = (unsigned int)f2bf(h2) | ((unsigned int)f2bf(h3) << 16);
        *(uint2*)&hb[(size_t)m * 64 + boff] = o;
    }
}

// ------- GEMM2 (MFMA bf16): [M,128] @ [128,48pad] -> bf16 [M,40] -------
// Input hb already carries the dinv pre-scale; no epilogue scaling needed.
__global__ __launch_bounds__(256) void k_gemm2_mfma(const ushort* __restrict__ hb,
                                                    const ushort* __restrict__ W2t,
                                                    ushort* __restrict__ h2s, int M) {
    int t = threadIdx.x;
    int wave = t >> 6, lane = t & 63;
    int lrow = lane & 15, quad = lane >> 4;
    int row0 = blockIdx.x * 64 + wave * 16;
    int rm = row0 + lrow;
    if (rm >= M) rm = M - 1;          // OOB rows never stored
    const ushort* pa = &hb[(size_t)rm * HID + quad * 8];
    float4v acc[3];
    acc[0] = (float4v)(0.f); acc[1] = (float4v)(0.f); acc[2] = (float4v)(0.f);
    #pragma unroll
    for (int k0 = 0; k0 < HID; k0 += 32) {
        short8 a = *(const short8*)(pa + k0);
        #pragma unroll
        for (int jj = 0; jj < 3; ++jj) {
            short8 b = *(const short8*)&W2t[(size_t)(jj * 16 + lrow) * HID
                                            + k0 + quad * 8];
            acc[jj] = __builtin_amdgcn_mfma_f32_16x16x32_bf16(a, b, acc[jj], 0, 0, 0);
        }
    }
    #pragma unroll
    for (int jj = 0; jj < 3; ++jj) {
        int cls = jj * 16 + lrow;
        #pragma unroll
        for (int r = 0; r < 4; ++r) {
            int node = row0 + quad * 4 + r;
            if (node < M && cls < NCLASS)
                h2s[(size_t)node * NCLASS + cls] = f2bf(acc[jj][r]);
        }
    }
}

// ------- layer-2 aggregation + bias + log_softmax ----
// 4 waves/block, one node/wave; 3 groups of 20 lanes each take every 3rd edge
// (240 B/gather-instruction vs 80 B), combined via shfl. Rows pre-scaled, so
// the inner loop is a pure sum.
__global__ __launch_bounds__(256) void k_agg2_final(const int* __restrict__ rowptr,
                                                    const int* __restrict__ rowend,
                                                    const int* __restrict__ col,
                                                    const float* __restrict__ dinv,
                                                    const unsigned int* __restrict__ h2p,
                                                    const float* __restrict__ b2,
                                                    float* __restrict__ out, int N) {
    int wv = threadIdx.x >> 6;
    int t  = threadIdx.x & 63;
    int m = blockIdx.x * 4 + wv;
    if (m >= N) m = N - 1;       // duplicate rows write identical bytes: benign
    float dm = dinv[m];
    int g = (t >= 40) ? 2 : ((t >= 20) ? 1 : 0);
    int u = t - g * 20;          // class pair {2u, 2u+1}
    bool act = t < 60;
    float vx = 0.f, vy = 0.f;
    if (t < 20) {                // self-loop term, group 0 only
        unsigned int v = h2p[(size_t)m * 20 + u];
        vx = blo(v);
        vy = bhi(v);
    }
    int j = rowptr[m] + g, jend = rowend[m];
    if (act) {
        for (; j + 3 < jend; j += 6) {
            int s0 = col[j], s1 = col[j + 3];
            unsigned int v0 = h2p[(size_t)s0 * 20 + u];
            unsigned int v1 = h2p[(size_t)s1 * 20 + u];
            vx += blo(v0); vy += bhi(v0);
            vx += blo(v1); vy += bhi(v1);
        }
        if (j < jend) {
            int s = col[j];
            unsigned int v = h2p[(size_t)s * 20 + u];
            vx += blo(v); vy += bhi(v);
        }
    }
    // combine the 3 group partials onto lanes 0..19
    vx += __shfl(vx, t + 20) + __shfl(vx, t + 40);
    vy += __shfl(vy, t + 20) + __shfl(vy, t + 40);
    bool w = t < 20;
    float lx = 0.f, ly = 0.f;
    if (w) {
        float2 bb = ((const float2*)b2)[u];
        lx = fmaf(vx, dm, bb.x);
        ly = fmaf(vy, dm, bb.y);
    }
    float mv = w ? fmaxf(lx, ly) : -INFINITY;
    #pragma unroll
    for (int off = 32; off; off >>= 1) mv = fmaxf(mv, __shfl_xor(mv, off));
    float ex = w ? (expf(lx - mv) + expf(ly - mv)) : 0.f;
    #pragma unroll
    for (int off = 32; off; off >>= 1) ex += __shfl_xor(ex, off);
    float lse = mv + logf(ex);
    if (w) ((float2*)out)[(size_t)m * 20 + u] = make_float2(lx - lse, ly - lse);
}

extern "C" void kernel_launch(void* const* d_in, const int* in_sizes, int n_in,
                              void* d_out, int out_size, void* d_ws, size_t ws_size,
                              hipStream_t stream) {
    const float* x  = (const float*)d_in[0];
    const int*   ei = (const int*)d_in[1];
    const float* W1 = (const float*)d_in[2];
    const float* b1 = (const float*)d_in[3];
    const float* W2 = (const float*)d_in[4];
    const float* b2 = (const float*)d_in[5];
    float* out = (float*)d_out;

    const int N = in_sizes[0] / IN_CH;   // 100000
    const int E = in_sizes[1] / 2;       // 1600000
    const int* src = ei;
    const int* dst = ei + E;

    const int NB_SCAN = (N + SCAN_CHUNK - 1) / SCAN_CHUNK;

    // workspace layout (4-byte words)
    size_t Npad = ((size_t)N + 127) / 128 * 128;
    float* ws = (float*)d_ws;
    float* dinv    = ws;                          // N floats
    int*   cnt     = (int*)(ws + Npad);           // N ints
    int*   rowptr  = (int*)(ws + 2 * Npad);       // N ints
    int*   cursor  = (int*)(ws + 3 * Npad);       // N ints (becomes row end)
    int*   bsum    = (int*)(ws + 4 * Npad);       // <=128 ints
    int*   col     = (int*)(ws + 4 * Npad + 128); // E ints
    size_t o_h1    = 4 * Npad + 128 + (size_t)E;
    unsigned int* h1b = (unsigned int*)(ws + o_h1);                   // N*64 words
    unsigned int* hb  = (unsigned int*)(ws + o_h1 + (size_t)N * 64);  // N*64 words
    unsigned int* h2p = (unsigned int*)(ws + o_h1 + (size_t)N * 128); // N*20 words
    ushort* W2t = (ushort*)(ws + o_h1 + (size_t)N * 148);             // 3072 words
    ushort* W1t = (ushort*)h2p;   // 128KB alias; dead before gemm2 writes h2p

    // ---- CSR build ----
    hipMemsetAsync(cnt, 0, (size_t)N * sizeof(int), stream);
    k_count<<<(E + 255) / 256, 256, 0, stream>>>(dst, E, cnt);
    k_scan_local<<<NB_SCAN, 256, 0, stream>>>(cnt, rowptr, bsum, N);
    k_scan_blocksums<<<1, 64, 0, stream>>>(bsum, NB_SCAN);
    k_scan_add_dinv<<<(N + 255) / 256, 256, 0, stream>>>(rowptr, cursor, bsum,
                                                         cnt, dinv, N);
    k_fill<<<8 * FILL_CHUNKS, 256, 0, stream>>>(src, dst, cursor, col, E, N);

    // ---- layer 1 ----
    k_wt<<<(HID * IN_CH + 48 * HID) / 256, 256, 0, stream>>>(W1, W2, W1t, W2t);
    k_gemm1_mfma<<<(N + GBM - 1) / GBM, 256, 0, stream>>>(x, W1t, dinv,
                                                          (ushort*)h1b, N);
    k_agg1_slice<<<8 * ((N + 15) / 16), 1024, 0, stream>>>(rowptr, cursor, col,
                                                           dinv, h1b, b1, hb, N);

    // ---- layer 2 ----
    k_gemm2_mfma<<<(N + 63) / 64, 256, 0, stream>>>((const ushort*)hb, W2t,
                                                    (ushort*)h2p, N);
    k_agg2_final<<<(N + 3) / 4, 256, 0, stream>>>(rowptr, cursor, col, dinv,
                                                  h2p, b2, out, N);
}

// Round 6
// 612.302 us; speedup vs baseline: 1.3869x; 1.3869x over previous
//
#include <hip/hip_runtime.h>
#include <math.h>

#define IN_CH 512
#define HID 128
#define NCLASS 40
#define SCAN_CHUNK 2048
#define FILL_CHUNKS 2048   // edge chunks for range-partitioned fill

typedef __attribute__((ext_vector_type(8))) short short8;
typedef __attribute__((ext_vector_type(4))) float float4v;

static __device__ inline ushort f2bf(float f) {
    unsigned int u = __float_as_uint(f);
    u += 0x7fffu + ((u >> 16) & 1u);
    return (ushort)(u >> 16);
}
// packed-bf16 halves -> float
static __device__ inline float blo(unsigned int u) { return __uint_as_float(u << 16); }
static __device__ inline float bhi(unsigned int u) { return __uint_as_float(u & 0xffff0000u); }

// ---------------- degree count ----------------
__global__ void k_count(const int* __restrict__ dst, int E, int* __restrict__ cnt) {
    int i = blockIdx.x * blockDim.x + threadIdx.x;
    if (i < E) atomicAdd(&cnt[dst[i]], 1);
}

// ---------------- exclusive scan of cnt -> rowptr ----------------
__global__ __launch_bounds__(256) void k_scan_local(const int* __restrict__ cnt,
                                                    int* __restrict__ rowptr,
                                                    int* __restrict__ blocksum, int n) {
    __shared__ int ssum[256];
    int b = blockIdx.x, t = threadIdx.x;
    int base = b * SCAN_CHUNK + t * 8;
    int v[8], s = 0;
    #pragma unroll
    for (int i = 0; i < 8; ++i) {
        int idx = base + i;
        v[i] = (idx < n) ? cnt[idx] : 0;
        s += v[i];
    }
    ssum[t] = s;
    __syncthreads();
    for (int off = 1; off < 256; off <<= 1) {
        int x = (t >= off) ? ssum[t - off] : 0;
        __syncthreads();
        ssum[t] += x;
        __syncthreads();
    }
    int run = ssum[t] - s;
    #pragma unroll
    for (int i = 0; i < 8; ++i) {
        int idx = base + i;
        if (idx < n) rowptr[idx] = run;
        run += v[i];
    }
    if (t == 255) blocksum[b] = ssum[255];
}

__global__ void k_scan_blocksums(int* blocksum, int nb) {
    if (threadIdx.x == 0 && blockIdx.x == 0) {
        int acc = 0;
        for (int i = 0; i < nb; ++i) { int v = blocksum[i]; blocksum[i] = acc; acc += v; }
    }
}

// scan finalize + dinv computation fused (both N-parallel over cnt/rowptr)
__global__ void k_scan_add_dinv(int* __restrict__ rowptr, int* __restrict__ cursor,
                                const int* __restrict__ blocksum,
                                const int* __restrict__ cnt,
                                float* __restrict__ dinv, int n) {
    int i = blockIdx.x * blockDim.x + threadIdx.x;
    if (i < n) {
        int r = rowptr[i] + blocksum[i / SCAN_CHUNK];
        rowptr[i] = r;
        cursor[i] = r;
        dinv[i] = rsqrtf((float)cnt[i] + 1.0f);
    }
}

// ------- CSR fill, dst-range partitioned for L2 locality (proven round-3 form) --
__global__ __launch_bounds__(256) void k_fill(const int* __restrict__ src,
                                              const int* __restrict__ dst,
                                              int* __restrict__ cursor,
                                              int* __restrict__ col, int E, int N) {
    int range = blockIdx.x & 7;
    int chunk = blockIdx.x >> 3;
    int r0 = (N >> 3) * range;
    int r1 = (range == 7) ? N : r0 + (N >> 3);
    int e0 = (int)((long long)E * chunk / FILL_CHUNKS);
    int e1 = (int)((long long)E * (chunk + 1) / FILL_CHUNKS);
    for (int e = e0 + threadIdx.x; e < e1; e += 256) {
        int d = dst[e];
        if (d >= r0 && d < r1) {
            int p = atomicAdd(&cursor[d], 1);
            col[p] = src[e];
        }
    }
}

// ---- W1 [512][128] -> W1t [128][512] bf16  +  W2 [128][40] -> W2t [48][128] ----
__global__ void k_wt(const float* __restrict__ W1, const float* __restrict__ W2,
                     ushort* __restrict__ W1t, ushort* __restrict__ W2t) {
    int i = blockIdx.x * blockDim.x + threadIdx.x;   // 65536 + 6144 = 71680
    if (i < HID * IN_CH) {
        int n = i >> 9;
        int k = i & 511;
        W1t[i] = f2bf(W1[k * HID + n]);
    } else {
        int q = i - HID * IN_CH;
        int n = q >> 7;
        int k = q & 127;
        float v = (n < NCLASS) ? W2[k * NCLASS + n] : 0.f;
        W2t[q] = f2bf(v);
    }
}

// ------- GEMM1 (MFMA bf16): [M,512] @ [512,128] -> dinv[m] * (.) -> bf16 -------
// Epilogue pre-scales each row by dinv[row]: downstream aggregation becomes a
// pure unweighted sum (no per-edge dinv load / multiply).
#define GBM 128
#define GBK 64
#define KP 72    // LDS row stride (bf16): 144 B -> worst 2-way bank aliasing (free)
__global__ __launch_bounds__(256) void k_gemm1_mfma(const float* __restrict__ X,
                                                    const ushort* __restrict__ W1t,
                                                    const float* __restrict__ dinv,
                                                    ushort* __restrict__ H, int M) {
    __shared__ ushort As[GBM * KP];   // 18.4 KB
    int t = threadIdx.x;
    int bm = blockIdx.x * GBM;
    int wave = t >> 6;
    int lane = t & 63;
    int m0w = (wave >> 1) * 64;
    int n0w = (wave & 1) * 64;
    int lrow = lane & 15;
    int quad = lane >> 4;

    float4v acc[4][4];
    #pragma unroll
    for (int i = 0; i < 4; ++i)
        #pragma unroll
        for (int j = 0; j < 4; ++j) acc[i][j] = (float4v)(0.f);

    int ar = t >> 1;
    int ah = (t & 1) * 32;
    int gmr = bm + ar;
    if (gmr >= M) gmr = M - 1;        // clamp: OOB C rows are never written
    const float* gA = &X[(size_t)gmr * IN_CH + ah];

    float4 pre[8];
    #pragma unroll
    for (int i = 0; i < 8; ++i) pre[i] = *(const float4*)(gA + i * 4);

    for (int k0 = 0; k0 < IN_CH; k0 += GBK) {
        #pragma unroll
        for (int i = 0; i < 4; ++i) {
            union { ushort u[8]; uint4 v; } pk;
            float4 f0 = pre[2 * i], f1 = pre[2 * i + 1];
            pk.u[0] = f2bf(f0.x); pk.u[1] = f2bf(f0.y);
            pk.u[2] = f2bf(f0.z); pk.u[3] = f2bf(f0.w);
            pk.u[4] = f2bf(f1.x); pk.u[5] = f2bf(f1.y);
            pk.u[6] = f2bf(f1.z); pk.u[7] = f2bf(f1.w);
            *(uint4*)&As[ar * KP + ah + i * 8] = pk.v;
        }
        if (k0 + GBK < IN_CH) {
            #pragma unroll
            for (int i = 0; i < 8; ++i)
                pre[i] = *(const float4*)(gA + k0 + GBK + i * 4);
        }
        __syncthreads();
        #pragma unroll
        for (int kk = 0; kk < GBK; kk += 32) {
            short8 af[4], bfr[4];
            #pragma unroll
            for (int j = 0; j < 4; ++j)
                bfr[j] = *(const short8*)&W1t[(size_t)(n0w + j * 16 + lrow) * IN_CH
                                              + k0 + kk + quad * 8];
            #pragma unroll
            for (int i = 0; i < 4; ++i)
                af[i] = *(const short8*)&As[(m0w + i * 16 + lrow) * KP + kk + quad * 8];
            #pragma unroll
            for (int i = 0; i < 4; ++i)
                #pragma unroll
                for (int j = 0; j < 4; ++j)
                    acc[i][j] = __builtin_amdgcn_mfma_f32_16x16x32_bf16(
                        af[i], bfr[j], acc[i][j], 0, 0, 0);
        }
        __syncthreads();
    }
    #pragma unroll
    for (int i = 0; i < 4; ++i) {
        #pragma unroll
        for (int r = 0; r < 4; ++r) {
            int gm = bm + m0w + i * 16 + quad * 4 + r;
            if (gm < M) {
                float di = dinv[gm];
                #pragma unroll
                for (int j = 0; j < 4; ++j)
                    H[(size_t)gm * HID + n0w + j * 16 + lrow] = f2bf(acc[i][j][r] * di);
            }
        }
    }
}

// ------- layer-1 aggregation: pure unweighted gather-sum of pre-scaled rows ----
// Proven round-3 structure (one node/wave, coalesced 256-B row reads, scalar
// wave-uniform col loads), deepened to 16 independent gather chains for MLP.
// Epilogue: *dm, +b1, relu, *dm (layer-2 pre-scale) -> packed bf16.
__global__ __launch_bounds__(256) void k_agg1(const int* __restrict__ rowptr,
                                              const int* __restrict__ rowend,
                                              const int* __restrict__ col,
                                              const float* __restrict__ dinv,
                                              const unsigned int* __restrict__ h1b,
                                              const float* __restrict__ b1,
                                              unsigned int* __restrict__ hb, int N) {
    int wv = threadIdx.x >> 6;
    int t  = threadIdx.x & 63;   // lane t owns channels {2t, 2t+1}
    int m = blockIdx.x * 4 + wv;
    if (m >= N) m = N - 1;       // duplicate rows write identical bytes: benign
    float dm = dinv[m];
    unsigned int sv = h1b[(size_t)m * 64 + t];
    float ax = blo(sv), ay = bhi(sv);
    float bx = 0.f, by = 0.f, cx = 0.f, cy = 0.f, dx = 0.f, dy = 0.f;
    int j = rowptr[m], jend = rowend[m];
    for (; j + 16 <= jend; j += 16) {
        int s0 = col[j],      s1 = col[j + 1],  s2 = col[j + 2],  s3 = col[j + 3];
        int s4 = col[j + 4],  s5 = col[j + 5],  s6 = col[j + 6],  s7 = col[j + 7];
        int s8 = col[j + 8],  s9 = col[j + 9],  sa = col[j + 10], sb = col[j + 11];
        int sc = col[j + 12], sd = col[j + 13], se = col[j + 14], sf = col[j + 15];
        unsigned int v0 = h1b[(size_t)s0 * 64 + t];
        unsigned int v1 = h1b[(size_t)s1 * 64 + t];
        unsigned int v2 = h1b[(size_t)s2 * 64 + t];
        unsigned int v3 = h1b[(size_t)s3 * 64 + t];
        unsigned int v4 = h1b[(size_t)s4 * 64 + t];
        unsigned int v5 = h1b[(size_t)s5 * 64 + t];
        unsigned int v6 = h1b[(size_t)s6 * 64 + t];
        unsigned int v7 = h1b[(size_t)s7 * 64 + t];
        unsigned int v8 = h1b[(size_t)s8 * 64 + t];
        unsigned int v9 = h1b[(size_t)s9 * 64 + t];
        unsigned int va = h1b[(size_t)sa * 64 + t];
        unsigned int vb = h1b[(size_t)sb * 64 + t];
        unsigned int vc = h1b[(size_t)sc * 64 + t];
        unsigned int vd = h1b[(size_t)sd * 64 + t];
        unsigned int ve = h1b[(size_t)se * 64 + t];
        unsigned int vf = h1b[(size_t)sf * 64 + t];
        ax += blo(v0); ay += bhi(v0);  bx += blo(v1); by += bhi(v1);
        cx += blo(v2); cy += bhi(v2);  dx += blo(v3); dy += bhi(v3);
        ax += blo(v4); ay += bhi(v4);  bx += blo(v5); by += bhi(v5);
        cx += blo(v6); cy += bhi(v6);  dx += blo(v7); dy += bhi(v7);
        ax += blo(v8); ay += bhi(v8);  bx += blo(v9); by += bhi(v9);
        cx += blo(va); cy += bhi(va);  dx += blo(vb); dy += bhi(vb);
        ax += blo(vc); ay += bhi(vc);  bx += blo(vd); by += bhi(vd);
        cx += blo(ve); cy += bhi(ve);  dx += blo(vf); dy += bhi(vf);
    }
    for (; j + 8 <= jend; j += 8) {
        int s0 = col[j],     s1 = col[j + 1], s2 = col[j + 2], s3 = col[j + 3];
        int s4 = col[j + 4], s5 = col[j + 5], s6 = col[j + 6], s7 = col[j + 7];
        unsigned int v0 = h1b[(size_t)s0 * 64 + t];
        unsigned int v1 = h1b[(size_t)s1 * 64 + t];
        unsigned int v2 = h1b[(size_t)s2 * 64 + t];
        unsigned int v3 = h1b[(size_t)s3 * 64 + t];
        unsigned int v4 = h1b[(size_t)s4 * 64 + t];
        unsigned int v5 = h1b[(size_t)s5 * 64 + t];
        unsigned int v6 = h1b[(size_t)s6 * 64 + t];
        unsigned int v7 = h1b[(size_t)s7 * 64 + t];
        ax += blo(v0); ay += bhi(v0);  bx += blo(v1); by += bhi(v1);
        cx += blo(v2); cy += bhi(v2);  dx += blo(v3); dy += bhi(v3);
        ax += blo(v4); ay += bhi(v4);  bx += blo(v5); by += bhi(v5);
        cx += blo(v6); cy += bhi(v6);  dx += blo(v7); dy += bhi(v7);
    }
    for (; j + 4 <= jend; j += 4) {
        int s0 = col[j], s1 = col[j + 1], s2 = col[j + 2], s3 = col[j + 3];
        unsigned int v0 = h1b[(size_t)s0 * 64 + t];
        unsigned int v1 = h1b[(size_t)s1 * 64 + t];
        unsigned int v2 = h1b[(size_t)s2 * 64 + t];
        unsigned int v3 = h1b[(size_t)s3 * 64 + t];
        ax += blo(v0); ay += bhi(v0);  bx += blo(v1); by += bhi(v1);
        cx += blo(v2); cy += bhi(v2);  dx += blo(v3); dy += bhi(v3);
    }
    for (; j < jend; ++j) {
        int s = col[j];
        unsigned int v = h1b[(size_t)s * 64 + t];
        ax += blo(v); ay += bhi(v);
    }
    ax += bx + cx + dx;
    ay += by + cy + dy;
    float2 bb = ((const float2*)b1)[t];
    float hx = fmaxf(fmaf(ax, dm, bb.x), 0.f) * dm;   // *dm pre-scales for layer 2
    float hy = fmaxf(fmaf(ay, dm, bb.y), 0.f) * dm;
    hb[(size_t)m * 64 + t] = (unsigned int)f2bf(hx) | ((unsigned int)f2bf(hy) << 16);
}

// ------- GEMM2 (MFMA bf16): [M,128] @ [128,48pad] -> bf16 [M,40] -------
// Input hb already carries the dinv pre-scale; no epilogue scaling needed.
__global__ __launch_bounds__(256) void k_gemm2_mfma(const ushort* __restrict__ hb,
                                                    const ushort* __restrict__ W2t,
                                                    ushort* __restrict__ h2s, int M) {
    int t = threadIdx.x;
    int wave = t >> 6, lane = t & 63;
    int lrow = lane & 15, quad = lane >> 4;
    int row0 = blockIdx.x * 64 + wave * 16;
    int rm = row0 + lrow;
    if (rm >= M) rm = M - 1;          // OOB rows never stored
    const ushort* pa = &hb[(size_t)rm * HID + quad * 8];
    float4v acc[3];
    acc[0] = (float4v)(0.f); acc[1] = (float4v)(0.f); acc[2] = (float4v)(0.f);
    #pragma unroll
    for (int k0 = 0; k0 < HID; k0 += 32) {
        short8 a = *(const short8*)(pa + k0);
        #pragma unroll
        for (int jj = 0; jj < 3; ++jj) {
            short8 b = *(const short8*)&W2t[(size_t)(jj * 16 + lrow) * HID
                                            + k0 + quad * 8];
            acc[jj] = __builtin_amdgcn_mfma_f32_16x16x32_bf16(a, b, acc[jj], 0, 0, 0);
        }
    }
    #pragma unroll
    for (int jj = 0; jj < 3; ++jj) {
        int cls = jj * 16 + lrow;
        #pragma unroll
        for (int r = 0; r < 4; ++r) {
            int node = row0 + quad * 4 + r;
            if (node < M && cls < NCLASS)
                h2s[(size_t)node * NCLASS + cls] = f2bf(acc[jj][r]);
        }
    }
}

// ------- layer-2 aggregation + bias + log_softmax ----
// 4 waves/block, one node/wave; 3 groups of 20 lanes each take every 3rd edge
// (240 B/gather-instruction vs 80 B), combined via shfl. Rows pre-scaled, so
// the inner loop is a pure sum.
__global__ __launch_bounds__(256) void k_agg2_final(const int* __restrict__ rowptr,
                                                    const int* __restrict__ rowend,
                                                    const int* __restrict__ col,
                                                    const float* __restrict__ dinv,
                                                    const unsigned int* __restrict__ h2p,
                                                    const float* __restrict__ b2,
                                                    float* __restrict__ out, int N) {
    int wv = threadIdx.x >> 6;
    int t  = threadIdx.x & 63;
    int m = blockIdx.x * 4 + wv;
    if (m >= N) m = N - 1;       // duplicate rows write identical bytes: benign
    float dm = dinv[m];
    int g = (t >= 40) ? 2 : ((t >= 20) ? 1 : 0);
    int u = t - g * 20;          // class pair {2u, 2u+1}
    bool act = t < 60;
    float vx = 0.f, vy = 0.f;
    if (t < 20) {                // self-loop term, group 0 only
        unsigned int v = h2p[(size_t)m * 20 + u];
        vx = blo(v);
        vy = bhi(v);
    }
    int j = rowptr[m] + g, jend = rowend[m];
    if (act) {
        for (; j + 3 < jend; j += 6) {
            int s0 = col[j], s1 = col[j + 3];
            unsigned int v0 = h2p[(size_t)s0 * 20 + u];
            unsigned int v1 = h2p[(size_t)s1 * 20 + u];
            vx += blo(v0); vy += bhi(v0);
            vx += blo(v1); vy += bhi(v1);
        }
        if (j < jend) {
            int s = col[j];
            unsigned int v = h2p[(size_t)s * 20 + u];
            vx += blo(v); vy += bhi(v);
        }
    }
    // combine the 3 group partials onto lanes 0..19
    vx += __shfl(vx, t + 20) + __shfl(vx, t + 40);
    vy += __shfl(vy, t + 20) + __shfl(vy, t + 40);
    bool w = t < 20;
    float lx = 0.f, ly = 0.f;
    if (w) {
        float2 bb = ((const float2*)b2)[u];
        lx = fmaf(vx, dm, bb.x);
        ly = fmaf(vy, dm, bb.y);
    }
    float mv = w ? fmaxf(lx, ly) : -INFINITY;
    #pragma unroll
    for (int off = 32; off; off >>= 1) mv = fmaxf(mv, __shfl_xor(mv, off));
    float ex = w ? (expf(lx - mv) + expf(ly - mv)) : 0.f;
    #pragma unroll
    for (int off = 32; off; off >>= 1) ex += __shfl_xor(ex, off);
    float lse = mv + logf(ex);
    if (w) ((float2*)out)[(size_t)m * 20 + u] = make_float2(lx - lse, ly - lse);
}

extern "C" void kernel_launch(void* const* d_in, const int* in_sizes, int n_in,
                              void* d_out, int out_size, void* d_ws, size_t ws_size,
                              hipStream_t stream) {
    const float* x  = (const float*)d_in[0];
    const int*   ei = (const int*)d_in[1];
    const float* W1 = (const float*)d_in[2];
    const float* b1 = (const float*)d_in[3];
    const float* W2 = (const float*)d_in[4];
    const float* b2 = (const float*)d_in[5];
    float* out = (float*)d_out;

    const int N = in_sizes[0] / IN_CH;   // 100000
    const int E = in_sizes[1] / 2;       // 1600000
    const int* src = ei;
    const int* dst = ei + E;

    const int NB_SCAN = (N + SCAN_CHUNK - 1) / SCAN_CHUNK;

    // workspace layout (4-byte words)
    size_t Npad = ((size_t)N + 127) / 128 * 128;
    float* ws = (float*)d_ws;
    float* dinv    = ws;                          // N floats
    int*   cnt     = (int*)(ws + Npad);           // N ints
    int*   rowptr  = (int*)(ws + 2 * Npad);       // N ints
    int*   cursor  = (int*)(ws + 3 * Npad);       // N ints (becomes row end)
    int*   bsum    = (int*)(ws + 4 * Npad);       // <=128 ints
    int*   col     = (int*)(ws + 4 * Npad + 128); // E ints
    size_t o_h1    = 4 * Npad + 128 + (size_t)E;
    unsigned int* h1b = (unsigned int*)(ws + o_h1);                   // N*64 words
    unsigned int* hb  = (unsigned int*)(ws + o_h1 + (size_t)N * 64);  // N*64 words
    unsigned int* h2p = (unsigned int*)(ws + o_h1 + (size_t)N * 128); // N*20 words
    ushort* W2t = (ushort*)(ws + o_h1 + (size_t)N * 148);             // 3072 words
    ushort* W1t = (ushort*)h2p;   // 128KB alias; dead before gemm2 writes h2p

    // ---- CSR build ----
    hipMemsetAsync(cnt, 0, (size_t)N * sizeof(int), stream);
    k_count<<<(E + 255) / 256, 256, 0, stream>>>(dst, E, cnt);
    k_scan_local<<<NB_SCAN, 256, 0, stream>>>(cnt, rowptr, bsum, N);
    k_scan_blocksums<<<1, 64, 0, stream>>>(bsum, NB_SCAN);
    k_scan_add_dinv<<<(N + 255) / 256, 256, 0, stream>>>(rowptr, cursor, bsum,
                                                         cnt, dinv, N);
    k_fill<<<8 * FILL_CHUNKS, 256, 0, stream>>>(src, dst, cursor, col, E, N);

    // ---- layer 1 ----
    k_wt<<<(HID * IN_CH + 48 * HID) / 256, 256, 0, stream>>>(W1, W2, W1t, W2t);
    k_gemm1_mfma<<<(N + GBM - 1) / GBM, 256, 0, stream>>>(x, W1t, dinv,
                                                          (ushort*)h1b, N);
    k_agg1<<<(N + 3) / 4, 256, 0, stream>>>(rowptr, cursor, col, dinv,
                                            h1b, b1, hb, N);

    // ---- layer 2 ----
    k_gemm2_mfma<<<(N + 63) / 64, 256, 0, stream>>>((const ushort*)hb, W2t,
                                                    (ushort*)h2p, N);
    k_agg2_final<<<(N + 3) / 4, 256, 0, stream>>>(rowptr, cursor, col, dinv,
                                                  h2p, b2, out, N);
}